// Round 1
// baseline (822.181 us; speedup 1.0000x reference)
//
#include <hip/hip_runtime.h>

#define NB 8
#define NT 512
#define NS 1024
#define NH 64
#define NE 64
#define NV 32000
#define BT 4096

typedef __attribute__((ext_vector_type(8))) short bf16x8;
typedef __attribute__((ext_vector_type(4))) float f32x4;
typedef unsigned short u16_t;
typedef unsigned int u32_t;

__device__ __forceinline__ u16_t f2bf(float f){
  union { float f; u32_t i; } v; v.f = f;
  return (u16_t)((v.i + 0x7fffu + ((v.i >> 16) & 1u)) >> 16);
}

__constant__ float kSQH = 0.70710678118654752440f;
#define SQH 0.70710678118654752440f
#define ATTN_SCALE 11.313708498984761f

// ---------------- weight prep ----------------
// convW [5][64][ic=64][oc=128] f32  ->  Wt [5][64][oc=128][ic=64] bf16
__global__ void k_prep_convw(const float* __restrict__ convW, u16_t* __restrict__ Wt){
  int khkw = blockIdx.x;                 // 0..319
  __shared__ float tile[64][129];        // [ic][oc]
  const float* src = convW + (size_t)khkw * 8192;
  for(int i = threadIdx.x; i < 8192; i += 256) tile[i >> 7][i & 127] = src[i];
  __syncthreads();
  u16_t* dst = Wt + (size_t)khkw * 8192;
  for(int i = threadIdx.x; i < 8192; i += 256) dst[i] = f2bf(tile[i & 63][i >> 6]); // i = oc*64+ic
}

// W3 [e=64][v=32000] f32 -> W3t [v][e] bf16
__global__ void k_prep_w3(const float* __restrict__ W3, u16_t* __restrict__ W3t){
  int v = blockIdx.x * 256 + threadIdx.x;
  if(v >= NV) return;
  u32_t pk[32];
  #pragma unroll
  for(int e = 0; e < 64; e += 2){
    u32_t lo = f2bf(W3[(size_t)e * NV + v]);
    u32_t hi = f2bf(W3[(size_t)(e + 1) * NV + v]);
    pk[e >> 1] = lo | (hi << 16);
  }
  u32_t* dst = (u32_t*)(W3t + (size_t)v * 64);
  #pragma unroll
  for(int i = 0; i < 32; i++) dst[i] = pk[i];
}

// ---------------- dl1 = relu(x@W1+b1) ----------------
__global__ void k_dl1(const float* __restrict__ X, const float* __restrict__ W,
                      const float* __restrict__ bias, float* __restrict__ out){
  int r0 = blockIdx.x * 4, tid = threadIdx.x;
  __shared__ float xs[4][64];
  xs[tid >> 6][tid & 63] = X[(size_t)r0 * 64 + tid];
  __syncthreads();
  int h = tid & 63, rr = tid >> 6;
  float acc = bias[h];
  #pragma unroll 16
  for(int e = 0; e < 64; e++) acc = fmaf(xs[rr][e], W[e * 64 + h], acc);
  out[(size_t)(r0 + rr) * 64 + h] = fmaxf(acc, 0.f);
}

// ---------------- y (f32) -> padded bf16 [8][576][64], zero outside t in [0,512) ----------------
__global__ void k_y2bf(const float* __restrict__ y, u16_t* __restrict__ ybf){
  int i = blockIdx.x * 256 + threadIdx.x;   // < 8*576*64
  int c = i & 63, r6 = i >> 6;
  int up = r6 % 576, b = r6 / 576;
  int t = up - 31;
  float v = (t >= 0 && t < NT) ? y[((size_t)b * NT + t) * 64 + c] : 0.f;
  ybf[i] = f2bf(v);
}

// ---------------- conv as implicit GEMM (per kh partials) ----------------
__global__ __launch_bounds__(256) void k_conv(const u16_t* __restrict__ ybf,
                                              const u16_t* __restrict__ Wt,
                                              float* __restrict__ part){
  int mt = blockIdx.x;       // 0..63  (b = mt/8, t0 = (mt%8)*64)
  int kh = blockIdx.y;       // 0..4
  int b = mt >> 3, t0 = (mt & 7) << 6;
  int bp = b + kh - 2;
  if(bp < 0 || bp >= NB) return;
  __shared__ u16_t strip[127 * 72];        // rows t0..t0+126 of ybf[bp], padded stride 72
  __shared__ u16_t wtile[2][128 * 72];     // [oc][ic] padded
  int tid = threadIdx.x;

  const u16_t* ysrc = ybf + ((size_t)bp * 576 + t0) * 64;
  for(int li = tid; li < 1016; li += 256)
    *(bf16x8*)(strip + (li >> 3) * 72 + (li & 7) * 8) = *(const bf16x8*)(ysrc + li * 8);

  const u16_t* wsrc = Wt + (size_t)kh * 64 * 8192;
  bf16x8 wreg[4];
  auto loadW = [&](int kw){
    const u16_t* p = wsrc + (size_t)kw * 8192;
    #pragma unroll
    for(int j = 0; j < 4; j++) wreg[j] = *(const bf16x8*)(p + (tid + j * 256) * 8);
  };
  auto storeW = [&](int bufi){
    u16_t* q = wtile[bufi];
    #pragma unroll
    for(int j = 0; j < 4; j++){
      int li = tid + j * 256;
      *(bf16x8*)(q + (li >> 3) * 72 + (li & 7) * 8) = wreg[j];
    }
  };
  loadW(0); storeW(0);
  __syncthreads();

  int lane = tid & 63;
  int l15 = lane & 15, lgp = lane >> 4;
  int wid = tid >> 6;
  int wm = wid >> 1, wn = wid & 1;
  f32x4 acc[2][4];
  #pragma unroll
  for(int m = 0; m < 2; m++)
    #pragma unroll
    for(int n = 0; n < 4; n++) acc[m][n] = (f32x4){0.f, 0.f, 0.f, 0.f};
  int arow0 = wm * 32 + l15;
  int koff = lgp * 8;

  for(int kw = 0; kw < 64; kw++){
    int bufi = kw & 1;
    if(kw < 63) loadW(kw + 1);
    const u16_t* wt = wtile[bufi];
    #pragma unroll
    for(int ks = 0; ks < 2; ks++){
      bf16x8 a0 = *(const bf16x8*)(strip + (arow0 + kw) * 72 + ks * 32 + koff);
      bf16x8 a1 = *(const bf16x8*)(strip + (arow0 + 16 + kw) * 72 + ks * 32 + koff);
      bf16x8 q0 = *(const bf16x8*)(wt + (wn * 64 + l15) * 72 + ks * 32 + koff);
      bf16x8 q1 = *(const bf16x8*)(wt + (wn * 64 + 16 + l15) * 72 + ks * 32 + koff);
      bf16x8 q2 = *(const bf16x8*)(wt + (wn * 64 + 32 + l15) * 72 + ks * 32 + koff);
      bf16x8 q3 = *(const bf16x8*)(wt + (wn * 64 + 48 + l15) * 72 + ks * 32 + koff);
      acc[0][0] = __builtin_amdgcn_mfma_f32_16x16x32_bf16(a0, q0, acc[0][0], 0, 0, 0);
      acc[0][1] = __builtin_amdgcn_mfma_f32_16x16x32_bf16(a0, q1, acc[0][1], 0, 0, 0);
      acc[0][2] = __builtin_amdgcn_mfma_f32_16x16x32_bf16(a0, q2, acc[0][2], 0, 0, 0);
      acc[0][3] = __builtin_amdgcn_mfma_f32_16x16x32_bf16(a0, q3, acc[0][3], 0, 0, 0);
      acc[1][0] = __builtin_amdgcn_mfma_f32_16x16x32_bf16(a1, q0, acc[1][0], 0, 0, 0);
      acc[1][1] = __builtin_amdgcn_mfma_f32_16x16x32_bf16(a1, q1, acc[1][1], 0, 0, 0);
      acc[1][2] = __builtin_amdgcn_mfma_f32_16x16x32_bf16(a1, q2, acc[1][2], 0, 0, 0);
      acc[1][3] = __builtin_amdgcn_mfma_f32_16x16x32_bf16(a1, q3, acc[1][3], 0, 0, 0);
    }
    if(kw < 63) storeW(bufi ^ 1);
    __syncthreads();
  }

  float* dst = part + ((size_t)kh * BT + (size_t)mt * 64) * 128;
  #pragma unroll
  for(int mf = 0; mf < 2; mf++)
    #pragma unroll
    for(int nf = 0; nf < 4; nf++)
      #pragma unroll
      for(int r = 0; r < 4; r++){
        int row = wm * 32 + mf * 16 + lgp * 4 + r;
        int col = wn * 64 + nf * 16 + l15;
        dst[row * 128 + col] = acc[mf][nf][r];
      }
}

// ---------------- GLU + residual ----------------
__global__ void k_glu(const float* __restrict__ part, const float* __restrict__ convb,
                      const float* __restrict__ ycur, float* __restrict__ ymid){
  int i = blockIdx.x * 256 + threadIdx.x;  // 4096*64
  int r = i >> 6, h = i & 63;
  int b = r >> 9;
  float ca = convb[h], cb = convb[64 + h];
  #pragma unroll
  for(int kh = 0; kh < 5; kh++){
    int bp2 = b + kh - 2;
    if(bp2 >= 0 && bp2 < NB){
      const float* p = part + ((size_t)kh * BT + r) * 128;
      ca += p[h]; cb += p[64 + h];
    }
  }
  float sig = 1.f / (1.f + __expf(-cb));
  ymid[i] = (ca * sig + ycur[i]) * SQH;
}

// ---------------- fused attention block (8 rows / WG) ----------------
__global__ __launch_bounds__(256) void k_attn(const float* __restrict__ ymid,
    const float* __restrict__ ea, const float* __restrict__ eo,
    const float* __restrict__ Wce, const float* __restrict__ bce,
    const float* __restrict__ Wec, const float* __restrict__ bec,
    float* __restrict__ ynext){
  int r0 = blockIdx.x * 8;
  int b = r0 >> 9;
  int tid = threadIdx.x;
  __shared__ float ym[8][64];
  __shared__ float pg[8][64];
  __shared__ float lg[8][1040];
  __shared__ float ech[128][68];
  __shared__ float red[8][33];
  __shared__ float inv8[8];
  __shared__ float aosm[8][64];

  for(int i = tid; i < 512; i += 256) ym[i >> 6][i & 63] = ymid[(size_t)r0 * 64 + i];
  __syncthreads();
  { // pg logits
    int h = tid & 63, rr = tid >> 6;
    #pragma unroll
    for(int k = 0; k < 2; k++){
      int r = rr + 4 * k;
      float acc = bce[h];
      #pragma unroll 16
      for(int e = 0; e < 64; e++) acc = fmaf(ym[r][e], Wce[e * 64 + h], acc);
      pg[r][h] = acc;
    }
  }
  __syncthreads();
  { // softmax over 64 (pg)
    int r = tid >> 5, j = tid & 31;
    float v1 = __expf(pg[r][j]), v2 = __expf(pg[r][j + 32]);
    pg[r][j] = v1; pg[r][j + 32] = v2;
    red[r][j] = v1 + v2;
  }
  __syncthreads();
  if(tid < 8){ float s = 0.f; for(int j = 0; j < 32; j++) s += red[tid][j]; inv8[tid] = 1.f / s; }
  __syncthreads();
  for(int i = tid; i < 512; i += 256) pg[i >> 6][i & 63] *= inv8[i >> 6];

  // logits over S in chunks of 128
  for(int c = 0; c < 8; c++){
    __syncthreads();
    const float* src = ea + ((size_t)b * NS + c * 128) * 64;
    for(int i4 = tid; i4 < 2048; i4 += 256){
      int s = i4 >> 4, e0 = (i4 & 15) * 4;
      *(float4*)&ech[s][e0] = *(const float4*)(src + i4 * 4);
    }
    __syncthreads();
    #pragma unroll
    for(int k = 0; k < 4; k++){
      int idx = tid + k * 256;
      int r = idx >> 7, s = idx & 127;
      float acc = 0.f;
      #pragma unroll
      for(int e0 = 0; e0 < 64; e0 += 4){
        float4 p4 = *(const float4*)&pg[r][e0];
        float4 e4 = *(const float4*)&ech[s][e0];
        acc = fmaf(p4.x, e4.x, acc); acc = fmaf(p4.y, e4.y, acc);
        acc = fmaf(p4.z, e4.z, acc); acc = fmaf(p4.w, e4.w, acc);
      }
      lg[r][c * 128 + s] = acc;
    }
  }
  __syncthreads();
  { // exp + row sums over S=1024
    int r = tid >> 5, j = tid & 31;
    float p = 0.f;
    for(int i = 0; i < 32; i++){ float v = __expf(lg[r][j + 32 * i]); lg[r][j + 32 * i] = v; p += v; }
    red[r][j] = p;
  }
  __syncthreads();
  if(tid < 8){ float s = 0.f; for(int j = 0; j < 32; j++) s += red[tid][j]; inv8[tid] = ATTN_SCALE / s; }
  __syncthreads();

  // ao = (attn @ eo) * scale, normalization folded into inv8
  float a0acc = 0.f, a1acc = 0.f;
  int ecol = tid & 63, rr2 = tid >> 6;
  for(int c = 0; c < 8; c++){
    __syncthreads();
    const float* src = eo + ((size_t)b * NS + c * 128) * 64;
    for(int i4 = tid; i4 < 2048; i4 += 256){
      int s = i4 >> 4, e0 = (i4 & 15) * 4;
      *(float4*)&ech[s][e0] = *(const float4*)(src + i4 * 4);
    }
    __syncthreads();
    #pragma unroll 4
    for(int s = 0; s < 128; s++){
      float ev = ech[s][ecol];
      a0acc = fmaf(lg[rr2][c * 128 + s], ev, a0acc);
      a1acc = fmaf(lg[rr2 + 4][c * 128 + s], ev, a1acc);
    }
  }
  aosm[rr2][ecol] = a0acc * inv8[rr2];
  aosm[rr2 + 4][ecol] = a1acc * inv8[rr2 + 4];
  __syncthreads();
  { // y_next logits = ao@Wec + bec
    int h = tid & 63, rr = tid >> 6;
    #pragma unroll
    for(int k = 0; k < 2; k++){
      int r = rr + 4 * k;
      float acc = bec[h];
      #pragma unroll 16
      for(int e = 0; e < 64; e++) acc = fmaf(aosm[r][e], Wec[e * 64 + h], acc);
      lg[r][h] = acc;
    }
  }
  __syncthreads();
  { // softmax over 64
    int r = tid >> 5, j = tid & 31;
    float v1 = __expf(lg[r][j]), v2 = __expf(lg[r][j + 32]);
    lg[r][j] = v1; lg[r][j + 32] = v2;
    red[r][j] = v1 + v2;
  }
  __syncthreads();
  if(tid < 8){ float s = 0.f; for(int j = 0; j < 32; j++) s += red[tid][j]; inv8[tid] = 1.f / s; }
  __syncthreads();
  for(int i = tid; i < 512; i += 256){
    int r = i >> 6, h = i & 63;
    ynext[(size_t)r0 * 64 + i] = lg[r][h] * inv8[r];
  }
}

// ---------------- y2 = relu(((y+dl1)*SQ)@W2+b2) -> bf16; zero esum ----------------
__global__ void k_w2(const float* __restrict__ y3, const float* __restrict__ dl1v,
                     const float* __restrict__ W2, const float* __restrict__ b2,
                     u16_t* __restrict__ y2bf, float* __restrict__ esum){
  int r0 = blockIdx.x * 4, tid = threadIdx.x;
  __shared__ float xs[4][64];
  xs[tid >> 6][tid & 63] = (y3[(size_t)r0 * 64 + tid] + dl1v[(size_t)r0 * 64 + tid]) * SQH;
  __syncthreads();
  int h = tid & 63, rr = tid >> 6;
  float acc = b2[h];
  #pragma unroll 16
  for(int e = 0; e < 64; e++) acc = fmaf(xs[rr][e], W2[e * 64 + h], acc);
  y2bf[(size_t)(r0 + rr) * 64 + h] = f2bf(fmaxf(acc, 0.f));
  if(tid < 4) esum[r0 + tid] = 0.f;
}

// ---------------- V-GEMM pass A: sum of exp(relu(logit)) per row ----------------
__global__ __launch_bounds__(256) void k_va(const u16_t* __restrict__ y2bf,
    const u16_t* __restrict__ W3t, const float* __restrict__ b3, float* __restrict__ esum){
  int mt = blockIdx.x, ns = blockIdx.y;
  int m0 = mt << 4;
  int tid = threadIdx.x, lane = tid & 63, w = tid >> 6;
  int l15 = lane & 15, lgp = lane >> 4;
  const u16_t* arow = y2bf + ((size_t)(m0 + l15) << 6) + lgp * 8;
  bf16x8 a0 = *(const bf16x8*)(arow);
  bf16x8 a1 = *(const bf16x8*)(arow + 32);
  float sums[4] = {0.f, 0.f, 0.f, 0.f};
  for(int it = 0; it < 25; it++){
    int nb = ns * 6400 + it * 256 + w * 64;
    #pragma unroll
    for(int f = 0; f < 4; f++){
      int n = nb + f * 16 + l15;
      const u16_t* bp2 = W3t + ((size_t)n << 6) + lgp * 8;
      bf16x8 q0 = *(const bf16x8*)(bp2);
      bf16x8 q1 = *(const bf16x8*)(bp2 + 32);
      f32x4 acc = {0.f, 0.f, 0.f, 0.f};
      acc = __builtin_amdgcn_mfma_f32_16x16x32_bf16(a0, q0, acc, 0, 0, 0);
      acc = __builtin_amdgcn_mfma_f32_16x16x32_bf16(a1, q1, acc, 0, 0, 0);
      float bias = b3[n];
      #pragma unroll
      for(int r = 0; r < 4; r++){
        float z = fmaxf(acc[r] + bias, 0.f);
        sums[r] += __expf(z);
      }
    }
  }
  #pragma unroll
  for(int r = 0; r < 4; r++){
    float v = sums[r];
    v += __shfl_xor(v, 1, 64); v += __shfl_xor(v, 2, 64);
    v += __shfl_xor(v, 4, 64); v += __shfl_xor(v, 8, 64);
    if(l15 == 0) atomicAdd(&esum[m0 + lgp * 4 + r], v);
  }
}

// ---------------- V-GEMM pass B: recompute + normalize + write ----------------
__global__ __launch_bounds__(256) void k_vb(const u16_t* __restrict__ y2bf,
    const u16_t* __restrict__ W3t, const float* __restrict__ b3,
    const float* __restrict__ esum, float* __restrict__ out){
  int mt = blockIdx.x, ns = blockIdx.y;
  int m0 = mt << 4;
  int tid = threadIdx.x, lane = tid & 63, w = tid >> 6;
  int l15 = lane & 15, lgp = lane >> 4;
  const u16_t* arow = y2bf + ((size_t)(m0 + l15) << 6) + lgp * 8;
  bf16x8 a0 = *(const bf16x8*)(arow);
  bf16x8 a1 = *(const bf16x8*)(arow + 32);
  float invs[4];
  #pragma unroll
  for(int r = 0; r < 4; r++) invs[r] = 1.f / esum[m0 + lgp * 4 + r];
  for(int it = 0; it < 25; it++){
    int nb = ns * 6400 + it * 256 + w * 64;
    #pragma unroll
    for(int f = 0; f < 4; f++){
      int n = nb + f * 16 + l15;
      const u16_t* bp2 = W3t + ((size_t)n << 6) + lgp * 8;
      bf16x8 q0 = *(const bf16x8*)(bp2);
      bf16x8 q1 = *(const bf16x8*)(bp2 + 32);
      f32x4 acc = {0.f, 0.f, 0.f, 0.f};
      acc = __builtin_amdgcn_mfma_f32_16x16x32_bf16(a0, q0, acc, 0, 0, 0);
      acc = __builtin_amdgcn_mfma_f32_16x16x32_bf16(a1, q1, acc, 0, 0, 0);
      float bias = b3[n];
      #pragma unroll
      for(int r = 0; r < 4; r++){
        float z = fmaxf(acc[r] + bias, 0.f);
        out[(size_t)(m0 + lgp * 4 + r) * NV + n] = __expf(z) * invs[r];
      }
    }
  }
}

extern "C" void kernel_launch(void* const* d_in, const int* in_sizes, int n_in,
                              void* d_out, int out_size, void* d_ws, size_t ws_size,
                              hipStream_t stream){
  const float* input_x = (const float*)d_in[0];
  const float* enc_out = (const float*)d_in[1];
  const float* enc_att = (const float*)d_in[2];
  const float* W1    = (const float*)d_in[3];
  const float* b1    = (const float*)d_in[4];
  const float* convW = (const float*)d_in[5];
  const float* convb = (const float*)d_in[6];
  const float* Wce   = (const float*)d_in[7];
  const float* bce   = (const float*)d_in[8];
  const float* Wec   = (const float*)d_in[9];
  const float* bec   = (const float*)d_in[10];
  const float* W2    = (const float*)d_in[11];
  const float* b2    = (const float*)d_in[12];
  const float* W3    = (const float*)d_in[13];
  const float* b3    = (const float*)d_in[14];

  char* ws = (char*)d_ws;
  u16_t* Wt    = (u16_t*)(ws);                 // 5,242,880 B
  u16_t* W3t   = (u16_t*)(ws + 5242880);       // 4,096,000 B
  float* dl1v  = (float*)(ws + 9338880);       // 1,048,576 B
  float* yA    = (float*)(ws + 10387456);      // 1,048,576 B
  float* yB    = (float*)(ws + 11436032);      // 1,048,576 B
  u16_t* ybf   = (u16_t*)(ws + 12484608);      //   589,824 B
  float* part  = (float*)(ws + 13074432);      // 10,485,760 B
  u16_t* y2bf  = (u16_t*)(ws + 23560192);      //   524,288 B
  float* esum  = (float*)(ws + 24084480);      //    16,384 B
  float* outp  = (float*)d_out;

  k_prep_convw<<<dim3(320), dim3(256), 0, stream>>>(convW, Wt);
  k_prep_w3<<<dim3(125), dim3(256), 0, stream>>>(W3, W3t);
  k_dl1<<<dim3(1024), dim3(256), 0, stream>>>(input_x, W1, b1, dl1v);

  const float* ycur = dl1v;
  for(int it = 0; it < 3; it++){
    k_y2bf<<<dim3(1152), dim3(256), 0, stream>>>(ycur, ybf);
    k_conv<<<dim3(64, 5), dim3(256), 0, stream>>>(ybf, Wt, part);
    k_glu<<<dim3(1024), dim3(256), 0, stream>>>(part, convb, ycur, yA);
    k_attn<<<dim3(512), dim3(256), 0, stream>>>(yA, enc_att, enc_out, Wce, bce, Wec, bec, yB);
    ycur = yB;
  }

  k_w2<<<dim3(1024), dim3(256), 0, stream>>>(yB, dl1v, W2, b2, y2bf, esum);
  k_va<<<dim3(256, 5), dim3(256), 0, stream>>>(y2bf, W3t, b3, esum);
  k_vb<<<dim3(256, 5), dim3(256), 0, stream>>>(y2bf, W3t, b3, esum, outp);
}

// Round 2
// 646.346 us; speedup vs baseline: 1.2720x; 1.2720x over previous
//
#include <hip/hip_runtime.h>

#define NB 8
#define NT 512
#define NS 1024
#define NV 32000
#define BT 4096
#define SQH 0.70710678118654752440f
#define ATTN_SCALE 11.313708498984761f

typedef __attribute__((ext_vector_type(8))) short bf16x8;
typedef __attribute__((ext_vector_type(4))) float f32x4;
typedef unsigned short u16_t;
typedef unsigned int u32_t;

#define MFMA16(a, b, c) __builtin_amdgcn_mfma_f32_16x16x32_bf16((a), (b), (c), 0, 0, 0)

typedef __attribute__((address_space(1))) const u32_t gas_u32;
typedef __attribute__((address_space(3))) u32_t las_u32;
__device__ __forceinline__ void gld_lds16(const u16_t* g, u16_t* l){
  __builtin_amdgcn_global_load_lds((gas_u32*)g, (las_u32*)l, 16, 0, 0);
}

__device__ __forceinline__ u16_t f2bf(float f){
  union { float f; u32_t i; } v; v.f = f;
  return (u16_t)((v.i + 0x7fffu + ((v.i >> 16) & 1u)) >> 16);
}

// ---------------- zero the pad rows of ybf (rows 0..30 and 543..575 per batch) ----
__global__ void k_zpad(u16_t* __restrict__ ybf){
  int i = blockIdx.x * 256 + threadIdx.x;    // 32768 total
  if(i >= 32768) return;
  int b = i >> 12, rem = i & 4095;
  int pr = rem >> 6, c = rem & 63;
  int row = pr < 31 ? pr : pr + 512;         // 0..30, 543..575
  ybf[((size_t)b * 576 + row) * 64 + c] = 0;
}

// ---------------- weight prep ----------------
// convW [5][64][ic=64][oc=128] f32 -> Wt: per (kh,kw) a linear 16KB image whose
// LDS copy (identity mapping via global_load_lds) has logical (oc,ic) at byte
// (oc*128 + ic*2) ^ ((oc&7)<<4)  — XOR-swizzled for conflict-free ds_read_b128.
__global__ void k_prep_convw(const float* __restrict__ convW, u16_t* __restrict__ Wt){
  int khkw = blockIdx.x;                 // 0..319
  __shared__ float tile[64][130];        // [ic][oc]
  const float* src = convW + (size_t)khkw * 8192;
  for(int i = threadIdx.x; i < 8192; i += 256) tile[i >> 7][i & 127] = src[i];
  __syncthreads();
  u16_t* dst = Wt + (size_t)khkw * 8192;
  for(int i = threadIdx.x; i < 8192; i += 256){
    int oc = i >> 6;
    int ic = (((i & 63) << 1) ^ ((oc & 7) << 4)) >> 1;
    dst[i] = f2bf(tile[ic][oc]);
  }
}

// W3 [e=64][v=32000] f32 -> W3t [v][e] bf16
__global__ void k_prep_w3(const float* __restrict__ W3, u16_t* __restrict__ W3t){
  int v = blockIdx.x * 256 + threadIdx.x;
  if(v >= NV) return;
  u32_t pk[32];
  #pragma unroll
  for(int e = 0; e < 64; e += 2){
    u32_t lo = f2bf(W3[(size_t)e * NV + v]);
    u32_t hi = f2bf(W3[(size_t)(e + 1) * NV + v]);
    pk[e >> 1] = lo | (hi << 16);
  }
  u32_t* dst = (u32_t*)(W3t + (size_t)v * 64);
  #pragma unroll
  for(int i = 0; i < 32; i++) dst[i] = pk[i];
}

// ---------------- dl1 = relu(x@W1+b1); also emit padded bf16 image ----------------
__global__ void k_dl1(const float* __restrict__ X, const float* __restrict__ W,
                      const float* __restrict__ bias, float* __restrict__ out,
                      u16_t* __restrict__ ybf){
  int r0 = blockIdx.x * 4, tid = threadIdx.x;
  __shared__ float xs[4][64];
  xs[tid >> 6][tid & 63] = X[(size_t)r0 * 64 + tid];
  __syncthreads();
  int h = tid & 63, rr = tid >> 6;
  float acc = bias[h];
  #pragma unroll 16
  for(int e = 0; e < 64; e++) acc = fmaf(xs[rr][e], W[e * 64 + h], acc);
  float v = fmaxf(acc, 0.f);
  int row = r0 + rr;
  out[(size_t)row * 64 + h] = v;
  int b = row >> 9, t = row & 511;
  ybf[((size_t)b * 576 + t + 31) * 64 + h] = f2bf(v);
}

// ---------------- conv as implicit GEMM (per-kh partials), async W staging -------
__global__ __launch_bounds__(256) void k_conv(const u16_t* __restrict__ ybf,
                                              const u16_t* __restrict__ Wt,
                                              float* __restrict__ part){
  int mt = blockIdx.x;       // 0..63
  int kh = blockIdx.y;       // 0..4
  int b = mt >> 3, t0 = (mt & 7) << 6;
  int bp = b + kh - 2;
  if(bp < 0 || bp >= NB) return;
  __shared__ u16_t strip[127 * 72];
  __shared__ u16_t wtile[2][8192];
  int tid = threadIdx.x;
  int lane = tid & 63, wid = tid >> 6;
  int l15 = lane & 15, lgp = lane >> 4;

  const u16_t* ysrc = ybf + ((size_t)bp * 576 + t0) * 64;
  for(int li = tid; li < 1016; li += 256)
    *(bf16x8*)(strip + (li >> 3) * 72 + (li & 7) * 8) = *(const bf16x8*)(ysrc + li * 8);

  const u16_t* wsrc = Wt + (size_t)kh * 64 * 8192;
  {
    const u16_t* g = wsrc + tid * 8;
    #pragma unroll
    for(int j = 0; j < 4; j++)
      gld_lds16(g + j * 2048, &wtile[0][j * 2048 + wid * 512]);
  }
  __syncthreads();

  int wm = wid >> 1, wn = wid & 1;
  f32x4 acc[2][4];
  #pragma unroll
  for(int m = 0; m < 2; m++)
    #pragma unroll
    for(int n = 0; n < 4; n++) acc[m][n] = (f32x4){0.f, 0.f, 0.f, 0.f};
  int arow0 = wm * 32 + l15;

  // precomputed swizzled u16 offsets for the 8 B-fragments
  int qoff[2][4];
  #pragma unroll
  for(int ks = 0; ks < 2; ks++)
    #pragma unroll
    for(int nf = 0; nf < 4; nf++){
      int oc = wn * 64 + nf * 16 + l15;
      int byte = (oc << 7) | (((ks << 6) | (lgp << 4)) ^ ((oc & 7) << 4));
      qoff[ks][nf] = byte >> 1;
    }

  for(int kw = 0; kw < 64; kw++){
    int cur = kw & 1;
    if(kw < 63){
      const u16_t* g = wsrc + (size_t)(kw + 1) * 8192 + tid * 8;
      #pragma unroll
      for(int j = 0; j < 4; j++)
        gld_lds16(g + j * 2048, &wtile[cur ^ 1][j * 2048 + wid * 512]);
    }
    const u16_t* wt = wtile[cur];
    #pragma unroll
    for(int ks = 0; ks < 2; ks++){
      bf16x8 a0 = *(const bf16x8*)(strip + (arow0 + kw) * 72 + ks * 32 + lgp * 8);
      bf16x8 a1 = *(const bf16x8*)(strip + (arow0 + 16 + kw) * 72 + ks * 32 + lgp * 8);
      bf16x8 q0 = *(const bf16x8*)(wt + qoff[ks][0]);
      bf16x8 q1 = *(const bf16x8*)(wt + qoff[ks][1]);
      bf16x8 q2 = *(const bf16x8*)(wt + qoff[ks][2]);
      bf16x8 q3 = *(const bf16x8*)(wt + qoff[ks][3]);
      acc[0][0] = MFMA16(a0, q0, acc[0][0]);
      acc[0][1] = MFMA16(a0, q1, acc[0][1]);
      acc[0][2] = MFMA16(a0, q2, acc[0][2]);
      acc[0][3] = MFMA16(a0, q3, acc[0][3]);
      acc[1][0] = MFMA16(a1, q0, acc[1][0]);
      acc[1][1] = MFMA16(a1, q1, acc[1][1]);
      acc[1][2] = MFMA16(a1, q2, acc[1][2]);
      acc[1][3] = MFMA16(a1, q3, acc[1][3]);
    }
    __syncthreads();   // drains global_load_lds (vmcnt 0) + protects buffer swap
  }

  float* dst = part + ((size_t)kh * BT + (size_t)mt * 64) * 128;
  #pragma unroll
  for(int mf = 0; mf < 2; mf++)
    #pragma unroll
    for(int nf = 0; nf < 4; nf++)
      #pragma unroll
      for(int r = 0; r < 4; r++){
        int row = wm * 32 + mf * 16 + lgp * 4 + r;
        int col = wn * 64 + nf * 16 + l15;
        dst[row * 128 + col] = acc[mf][nf][r];
      }
}

// ---------------- GLU + residual ----------------
__global__ void k_glu(const float* __restrict__ part, const float* __restrict__ convb,
                      const float* __restrict__ ycur, float* __restrict__ ymid){
  int i = blockIdx.x * 256 + threadIdx.x;  // 4096*64
  int r = i >> 6, h = i & 63;
  int b = r >> 9;
  float ca = convb[h], cb = convb[64 + h];
  #pragma unroll
  for(int kh = 0; kh < 5; kh++){
    int bp2 = b + kh - 2;
    if(bp2 >= 0 && bp2 < NB){
      const float* p = part + ((size_t)kh * BT + r) * 128;
      ca += p[h]; cb += p[64 + h];
    }
  }
  float sig = 1.f / (1.f + __expf(-cb));
  ymid[i] = (ca * sig + ycur[i]) * SQH;
}

// ---------------- fused attention block (8 rows / WG) ----------------
__global__ __launch_bounds__(256) void k_attn(const float* __restrict__ ymid,
    const float* __restrict__ ea, const float* __restrict__ eo,
    const float* __restrict__ Wce, const float* __restrict__ bce,
    const float* __restrict__ Wec, const float* __restrict__ bec,
    float* __restrict__ ynext, u16_t* __restrict__ ybf){
  int r0 = blockIdx.x * 8;
  int b = r0 >> 9;
  int tid = threadIdx.x;
  __shared__ float ym[8][64];
  __shared__ float pg[8][64];
  __shared__ float lg[8][1040];
  __shared__ float ech[128][68];
  __shared__ float inv8[8];
  __shared__ float aosm[8][64];

  for(int i = tid; i < 512; i += 256) ym[i >> 6][i & 63] = ymid[(size_t)r0 * 64 + i];
  __syncthreads();
  { // pg logits
    int h = tid & 63, rr = tid >> 6;
    #pragma unroll
    for(int k = 0; k < 2; k++){
      int r = rr + 4 * k;
      float acc = bce[h];
      #pragma unroll 16
      for(int e = 0; e < 64; e++) acc = fmaf(ym[r][e], Wce[e * 64 + h], acc);
      pg[r][h] = acc;
    }
  }
  __syncthreads();
  { // softmax over 64 (pg): 32-lane shfl reduce
    int r = tid >> 5, j = tid & 31;
    float v1 = __expf(pg[r][j]), v2 = __expf(pg[r][j + 32]);
    pg[r][j] = v1; pg[r][j + 32] = v2;
    float s = v1 + v2;
    s += __shfl_xor(s, 1); s += __shfl_xor(s, 2); s += __shfl_xor(s, 4);
    s += __shfl_xor(s, 8); s += __shfl_xor(s, 16);
    if(j == 0) inv8[r] = 1.f / s;
  }
  __syncthreads();
  for(int i = tid; i < 512; i += 256) pg[i >> 6][i & 63] *= inv8[i >> 6];

  // logits over S in chunks of 128
  for(int c = 0; c < 8; c++){
    __syncthreads();
    const float* src = ea + ((size_t)b * NS + c * 128) * 64;
    for(int i4 = tid; i4 < 2048; i4 += 256){
      int s = i4 >> 4, e0 = (i4 & 15) * 4;
      *(float4*)&ech[s][e0] = *(const float4*)(src + i4 * 4);
    }
    __syncthreads();
    #pragma unroll
    for(int k = 0; k < 4; k++){
      int idx = tid + k * 256;
      int r = idx >> 7, s = idx & 127;
      float acc = 0.f;
      #pragma unroll
      for(int e0 = 0; e0 < 64; e0 += 4){
        float4 p4 = *(const float4*)&pg[r][e0];
        float4 e4 = *(const float4*)&ech[s][e0];
        acc = fmaf(p4.x, e4.x, acc); acc = fmaf(p4.y, e4.y, acc);
        acc = fmaf(p4.z, e4.z, acc); acc = fmaf(p4.w, e4.w, acc);
      }
      lg[r][c * 128 + s] = acc;
    }
  }
  __syncthreads();
  { // exp + row sums over S=1024
    int r = tid >> 5, j = tid & 31;
    float p = 0.f;
    for(int i = 0; i < 32; i++){ float v = __expf(lg[r][j + 32 * i]); lg[r][j + 32 * i] = v; p += v; }
    p += __shfl_xor(p, 1); p += __shfl_xor(p, 2); p += __shfl_xor(p, 4);
    p += __shfl_xor(p, 8); p += __shfl_xor(p, 16);
    if(j == 0) inv8[r] = ATTN_SCALE / p;
  }
  __syncthreads();

  // ao = (attn @ eo) * scale, normalization folded into inv8
  float a0acc = 0.f, a1acc = 0.f;
  int ecol = tid & 63, rr2 = tid >> 6;
  for(int c = 0; c < 8; c++){
    __syncthreads();
    const float* src = eo + ((size_t)b * NS + c * 128) * 64;
    for(int i4 = tid; i4 < 2048; i4 += 256){
      int s = i4 >> 4, e0 = (i4 & 15) * 4;
      *(float4*)&ech[s][e0] = *(const float4*)(src + i4 * 4);
    }
    __syncthreads();
    #pragma unroll 4
    for(int s = 0; s < 128; s++){
      float ev = ech[s][ecol];
      a0acc = fmaf(lg[rr2][c * 128 + s], ev, a0acc);
      a1acc = fmaf(lg[rr2 + 4][c * 128 + s], ev, a1acc);
    }
  }
  aosm[rr2][ecol] = a0acc * inv8[rr2];
  aosm[rr2 + 4][ecol] = a1acc * inv8[rr2 + 4];
  __syncthreads();
  { // y_next logits = ao@Wec + bec
    int h = tid & 63, rr = tid >> 6;
    #pragma unroll
    for(int k = 0; k < 2; k++){
      int r = rr + 4 * k;
      float acc = bec[h];
      #pragma unroll 16
      for(int e = 0; e < 64; e++) acc = fmaf(aosm[r][e], Wec[e * 64 + h], acc);
      lg[r][h] = acc;
    }
  }
  __syncthreads();
  { // softmax over 64
    int r = tid >> 5, j = tid & 31;
    float v1 = __expf(lg[r][j]), v2 = __expf(lg[r][j + 32]);
    lg[r][j] = v1; lg[r][j + 32] = v2;
    float s = v1 + v2;
    s += __shfl_xor(s, 1); s += __shfl_xor(s, 2); s += __shfl_xor(s, 4);
    s += __shfl_xor(s, 8); s += __shfl_xor(s, 16);
    if(j == 0) inv8[r] = 1.f / s;
  }
  __syncthreads();
  for(int i = tid; i < 512; i += 256){
    int r = i >> 6, h = i & 63;
    float v = lg[r][h] * inv8[r];
    int row = r0 + r;
    ynext[(size_t)row * 64 + h] = v;
    int t = row & 511;
    ybf[((size_t)(row >> 9) * 576 + t + 31) * 64 + h] = f2bf(v);
  }
}

// ---------------- y2 = relu(((y+dl1)*SQ)@W2+b2) -> bf16; zero esum ----------------
__global__ void k_w2(const float* __restrict__ y3, const float* __restrict__ dl1v,
                     const float* __restrict__ W2, const float* __restrict__ b2,
                     u16_t* __restrict__ y2bf, float* __restrict__ esum){
  int r0 = blockIdx.x * 4, tid = threadIdx.x;
  __shared__ float xs[4][64];
  xs[tid >> 6][tid & 63] = (y3[(size_t)r0 * 64 + tid] + dl1v[(size_t)r0 * 64 + tid]) * SQH;
  __syncthreads();
  int h = tid & 63, rr = tid >> 6;
  float acc = b2[h];
  #pragma unroll 16
  for(int e = 0; e < 64; e++) acc = fmaf(xs[rr][e], W2[e * 64 + h], acc);
  y2bf[(size_t)(r0 + rr) * 64 + h] = f2bf(fmaxf(acc, 0.f));
  if(tid < 4) esum[r0 + tid] = 0.f;
}

// ---------------- V-GEMM pass A: sum of exp(relu(logit)) per row (M-tile 64) -----
__global__ __launch_bounds__(256) void k_va(const u16_t* __restrict__ y2bf,
    const u16_t* __restrict__ W3t, const float* __restrict__ b3, float* __restrict__ esum){
  int m0 = blockIdx.x << 6, ns = blockIdx.y;
  int tid = threadIdx.x, lane = tid & 63, w = tid >> 6;
  int l15 = lane & 15, lgp = lane >> 4;
  bf16x8 a[4][2];
  #pragma unroll
  for(int mg = 0; mg < 4; mg++){
    const u16_t* ar = y2bf + ((size_t)(m0 + mg * 16 + l15) << 6) + lgp * 8;
    a[mg][0] = *(const bf16x8*)ar;
    a[mg][1] = *(const bf16x8*)(ar + 32);
  }
  float sums[4][4];
  #pragma unroll
  for(int mg = 0; mg < 4; mg++)
    #pragma unroll
    for(int r = 0; r < 4; r++) sums[mg][r] = 0.f;

  int nb0 = ns * 1600 + w * 400;
  for(int fi = 0; fi < 25; fi++){
    int n = nb0 + fi * 16 + l15;
    const u16_t* bp2 = W3t + ((size_t)n << 6) + lgp * 8;
    bf16x8 q0 = *(const bf16x8*)bp2;
    bf16x8 q1 = *(const bf16x8*)(bp2 + 32);
    float bias = b3[n];
    #pragma unroll
    for(int mg = 0; mg < 4; mg++){
      f32x4 acc = {0.f, 0.f, 0.f, 0.f};
      acc = MFMA16(a[mg][0], q0, acc);
      acc = MFMA16(a[mg][1], q1, acc);
      #pragma unroll
      for(int r = 0; r < 4; r++){
        float z = fmaxf(acc[r] + bias, 0.f);
        sums[mg][r] += __expf(z);
      }
    }
  }
  #pragma unroll
  for(int mg = 0; mg < 4; mg++)
    #pragma unroll
    for(int r = 0; r < 4; r++){
      float v = sums[mg][r];
      v += __shfl_xor(v, 1); v += __shfl_xor(v, 2);
      v += __shfl_xor(v, 4); v += __shfl_xor(v, 8);
      if(l15 == 0) atomicAdd(&esum[m0 + mg * 16 + lgp * 4 + r], v);
    }
}

// ---------------- V-GEMM pass B: recompute + normalize + coalesced write ---------
__global__ __launch_bounds__(256) void k_vb(const u16_t* __restrict__ y2bf,
    const u16_t* __restrict__ W3t, const float* __restrict__ b3,
    const float* __restrict__ esum, float* __restrict__ out){
  int m0 = blockIdx.x << 6, ns = blockIdx.y;
  int tid = threadIdx.x, lane = tid & 63, w = tid >> 6;
  int l15 = lane & 15, lgp = lane >> 4;
  __shared__ float obuf[64][84];
  bf16x8 a[4][2];
  #pragma unroll
  for(int mg = 0; mg < 4; mg++){
    const u16_t* ar = y2bf + ((size_t)(m0 + mg * 16 + l15) << 6) + lgp * 8;
    a[mg][0] = *(const bf16x8*)ar;
    a[mg][1] = *(const bf16x8*)(ar + 32);
  }
  float invs[4][4];
  #pragma unroll
  for(int mg = 0; mg < 4; mg++)
    #pragma unroll
    for(int r = 0; r < 4; r++) invs[mg][r] = 1.f / esum[m0 + mg * 16 + lgp * 4 + r];

  int cb0 = ns * 1600;
  for(int si = 0; si < 25; si++){
    int cb = cb0 + si * 64;
    int n = cb + w * 16 + l15;
    const u16_t* bp2 = W3t + ((size_t)n << 6) + lgp * 8;
    bf16x8 q0 = *(const bf16x8*)bp2;
    bf16x8 q1 = *(const bf16x8*)(bp2 + 32);
    float bias = b3[n];
    #pragma unroll
    for(int mg = 0; mg < 4; mg++){
      f32x4 acc = {0.f, 0.f, 0.f, 0.f};
      acc = MFMA16(a[mg][0], q0, acc);
      acc = MFMA16(a[mg][1], q1, acc);
      #pragma unroll
      for(int r = 0; r < 4; r++){
        float z = fmaxf(acc[r] + bias, 0.f);
        obuf[mg * 16 + lgp * 4 + r][w * 16 + l15] = __expf(z) * invs[mg][r];
      }
    }
    __syncthreads();
    #pragma unroll
    for(int p = 0; p < 4; p++){
      int row = p * 16 + (tid >> 4);
      float4 v = *(const float4*)&obuf[row][(tid & 15) * 4];
      *(float4*)&out[(size_t)(m0 + row) * NV + cb + (tid & 15) * 4] = v;
    }
    __syncthreads();
  }
}

extern "C" void kernel_launch(void* const* d_in, const int* in_sizes, int n_in,
                              void* d_out, int out_size, void* d_ws, size_t ws_size,
                              hipStream_t stream){
  const float* input_x = (const float*)d_in[0];
  const float* enc_out = (const float*)d_in[1];
  const float* enc_att = (const float*)d_in[2];
  const float* W1    = (const float*)d_in[3];
  const float* b1    = (const float*)d_in[4];
  const float* convW = (const float*)d_in[5];
  const float* convb = (const float*)d_in[6];
  const float* Wce   = (const float*)d_in[7];
  const float* bce   = (const float*)d_in[8];
  const float* Wec   = (const float*)d_in[9];
  const float* bec   = (const float*)d_in[10];
  const float* W2    = (const float*)d_in[11];
  const float* b2    = (const float*)d_in[12];
  const float* W3    = (const float*)d_in[13];
  const float* b3    = (const float*)d_in[14];

  char* ws = (char*)d_ws;
  u16_t* Wt    = (u16_t*)(ws);                 // 5,242,880 B
  u16_t* W3t   = (u16_t*)(ws + 5242880);       // 4,096,000 B
  float* dl1v  = (float*)(ws + 9338880);       // 1,048,576 B
  float* yA    = (float*)(ws + 10387456);      // 1,048,576 B
  float* yB    = (float*)(ws + 11436032);      // 1,048,576 B
  u16_t* ybf   = (u16_t*)(ws + 12484608);      //   589,824 B
  float* part  = (float*)(ws + 13074432);      // 10,485,760 B
  u16_t* y2bf  = (u16_t*)(ws + 23560192);      //   524,288 B
  float* esum  = (float*)(ws + 24084480);      //    16,384 B
  float* outp  = (float*)d_out;

  k_zpad<<<dim3(128), dim3(256), 0, stream>>>(ybf);
  k_prep_convw<<<dim3(320), dim3(256), 0, stream>>>(convW, Wt);
  k_prep_w3<<<dim3(125), dim3(256), 0, stream>>>(W3, W3t);
  k_dl1<<<dim3(1024), dim3(256), 0, stream>>>(input_x, W1, b1, dl1v, ybf);

  const float* ycur = dl1v;
  for(int it = 0; it < 3; it++){
    k_conv<<<dim3(64, 5), dim3(256), 0, stream>>>(ybf, Wt, part);
    k_glu<<<dim3(1024), dim3(256), 0, stream>>>(part, convb, ycur, yA);
    k_attn<<<dim3(512), dim3(256), 0, stream>>>(yA, enc_att, enc_out, Wce, bce, Wec, bec, yB, ybf);
    ycur = yB;
  }

  k_w2<<<dim3(1024), dim3(256), 0, stream>>>(yB, dl1v, W2, b2, y2bf, esum);
  k_va<<<dim3(64, 20), dim3(256), 0, stream>>>(y2bf, W3t, b3, esum);
  k_vb<<<dim3(64, 20), dim3(256), 0, stream>>>(y2bf, W3t, b3, esum, outp);
}

// Round 3
// 426.422 us; speedup vs baseline: 1.9281x; 1.5157x over previous
//
#include <hip/hip_runtime.h>

#define NB 8
#define NT 512
#define NS 1024
#define NV 32000
#define BT 4096
#define SQH 0.70710678118654752440f
#define ATTN_SCALE 11.313708498984761f

typedef __attribute__((ext_vector_type(8))) short bf16x8;
typedef __attribute__((ext_vector_type(4))) float f32x4;
typedef unsigned short u16_t;
typedef unsigned int u32_t;

#define MFMA16(a, b, c) __builtin_amdgcn_mfma_f32_16x16x32_bf16((a), (b), (c), 0, 0, 0)

typedef __attribute__((address_space(1))) const u32_t gas_u32;
typedef __attribute__((address_space(3))) u32_t las_u32;
__device__ __forceinline__ void gld_lds16(const u16_t* g, u16_t* l){
  __builtin_amdgcn_global_load_lds((gas_u32*)g, (las_u32*)l, 16, 0, 0);
}

__device__ __forceinline__ u16_t f2bf(float f){
  union { float f; u32_t i; } v; v.f = f;
  return (u16_t)((v.i + 0x7fffu + ((v.i >> 16) & 1u)) >> 16);
}

// ---------------- zero the pad rows of ybf ----------------
__global__ void k_zpad(u16_t* __restrict__ ybf){
  int i = blockIdx.x * 256 + threadIdx.x;    // 32768 total
  if(i >= 32768) return;
  int b = i >> 12, rem = i & 4095;
  int pr = rem >> 6, c = rem & 63;
  int row = pr < 31 ? pr : pr + 512;         // 0..30, 543..575
  ybf[((size_t)b * 576 + row) * 64 + c] = 0;
}

// ---------------- weight prep: convW -> swizzled bf16 image ----------------
__global__ void k_prep_convw(const float* __restrict__ convW, u16_t* __restrict__ Wt){
  int khkw = blockIdx.x;                 // 0..319
  __shared__ float tile[64][130];        // [ic][oc]
  const float* src = convW + (size_t)khkw * 8192;
  for(int i = threadIdx.x; i < 8192; i += 256) tile[i >> 7][i & 127] = src[i];
  __syncthreads();
  u16_t* dst = Wt + (size_t)khkw * 8192;
  for(int i = threadIdx.x; i < 8192; i += 256){
    int oc = i >> 6;
    int ic = (((i & 63) << 1) ^ ((oc & 7) << 4)) >> 1;
    dst[i] = f2bf(tile[ic][oc]);
  }
}

// W3 [e=64][v=32000] f32 -> W3t [v][e] bf16
__global__ void k_prep_w3(const float* __restrict__ W3, u16_t* __restrict__ W3t){
  int v = blockIdx.x * 256 + threadIdx.x;
  if(v >= NV) return;
  u32_t pk[32];
  #pragma unroll
  for(int e = 0; e < 64; e += 2){
    u32_t lo = f2bf(W3[(size_t)e * NV + v]);
    u32_t hi = f2bf(W3[(size_t)(e + 1) * NV + v]);
    pk[e >> 1] = lo | (hi << 16);
  }
  u32_t* dst = (u32_t*)(W3t + (size_t)v * 64);
  #pragma unroll
  for(int i = 0; i < 32; i++) dst[i] = pk[i];
}

// ---------------- prep: ea -> bf16 [b][s][e]; eo -> bf16 transposed [b][e][s] ----
__global__ void k_prep_ea(const float* __restrict__ ea, const float* __restrict__ eo,
                          u16_t* __restrict__ eabf, u16_t* __restrict__ eoT){
  int blk = blockIdx.x;           // 0..127
  int b = blk >> 4, s0 = (blk & 15) << 6;
  int tid = threadIdx.x;
  __shared__ float tile[64][65];
  const float* easrc = ea + ((size_t)b * NS + s0) * 64;
  u16_t* eadst = eabf + ((size_t)b * NS + s0) * 64;
  for(int i = tid; i < 512; i += 256){
    float4 f0 = *(const float4*)(easrc + i * 8);
    float4 f1 = *(const float4*)(easrc + i * 8 + 4);
    union { u32_t u[4]; bf16x8 v; } pk;
    pk.u[0] = f2bf(f0.x) | ((u32_t)f2bf(f0.y) << 16);
    pk.u[1] = f2bf(f0.z) | ((u32_t)f2bf(f0.w) << 16);
    pk.u[2] = f2bf(f1.x) | ((u32_t)f2bf(f1.y) << 16);
    pk.u[3] = f2bf(f1.z) | ((u32_t)f2bf(f1.w) << 16);
    *(bf16x8*)(eadst + i * 8) = pk.v;
  }
  const float* eosrc = eo + ((size_t)b * NS + s0) * 64;
  for(int i = tid; i < 1024; i += 256){
    int s = i >> 4, e0 = (i & 15) * 4;
    float4 f = *(const float4*)(eosrc + s * 64 + e0);
    tile[s][e0] = f.x; tile[s][e0 + 1] = f.y; tile[s][e0 + 2] = f.z; tile[s][e0 + 3] = f.w;
  }
  __syncthreads();
  for(int i = tid; i < 512; i += 256){
    int e = i >> 3, sc = (i & 7) * 8;
    union { u32_t u[4]; bf16x8 v; } pk;
    #pragma unroll
    for(int j = 0; j < 4; j++){
      float lo = tile[sc + 2 * j][e], hi = tile[sc + 2 * j + 1][e];
      pk.u[j] = f2bf(lo) | ((u32_t)f2bf(hi) << 16);
    }
    *(bf16x8*)(eoT + ((size_t)b * 64 + e) * NS + s0 + sc) = pk.v;
  }
}

// ---------------- dl1 = relu(x@W1+b1); also emit padded bf16 image ----------------
__global__ void k_dl1(const float* __restrict__ X, const float* __restrict__ W,
                      const float* __restrict__ bias, float* __restrict__ out,
                      u16_t* __restrict__ ybf){
  int r0 = blockIdx.x * 4, tid = threadIdx.x;
  __shared__ float xs[4][64];
  xs[tid >> 6][tid & 63] = X[(size_t)r0 * 64 + tid];
  __syncthreads();
  int h = tid & 63, rr = tid >> 6;
  float acc = bias[h];
  #pragma unroll 16
  for(int e = 0; e < 64; e++) acc = fmaf(xs[rr][e], W[e * 64 + h], acc);
  float v = fmaxf(acc, 0.f);
  int row = r0 + rr;
  out[(size_t)row * 64 + h] = v;
  int b = row >> 9, t = row & 511;
  ybf[((size_t)b * 576 + t + 31) * 64 + h] = f2bf(v);
}

// ---------------- conv as implicit GEMM, counted-vmcnt double-buffer -------------
__global__ __launch_bounds__(256) void k_conv(const u16_t* __restrict__ ybf,
                                              const u16_t* __restrict__ Wt,
                                              float* __restrict__ part){
  int mt = blockIdx.x;       // 0..63
  int kh = blockIdx.y;       // 0..4
  int b = mt >> 3, t0 = (mt & 7) << 6;
  int bp = b + kh - 2;
  if(bp < 0 || bp >= NB) return;
  __shared__ u16_t strip[127 * 72];
  __shared__ u16_t wtile[2][8192];
  int tid = threadIdx.x;
  int lane = tid & 63, wid = tid >> 6;
  int l15 = lane & 15, lgp = lane >> 4;

  const u16_t* ysrc = ybf + ((size_t)bp * 576 + t0) * 64;
  for(int li = tid; li < 1016; li += 256)
    *(bf16x8*)(strip + (li >> 3) * 72 + (li & 7) * 8) = *(const bf16x8*)(ysrc + li * 8);

  const u16_t* wsrc = Wt + (size_t)kh * 64 * 8192;
  {
    const u16_t* g = wsrc + tid * 8;
    #pragma unroll
    for(int j = 0; j < 4; j++)
      gld_lds16(g + j * 2048, &wtile[0][j * 2048 + wid * 512]);
  }
  __syncthreads();   // one-time full drain (strip writes + buf0 loads)

  int wm = wid >> 1, wn = wid & 1;
  f32x4 acc[2][4];
  #pragma unroll
  for(int m = 0; m < 2; m++)
    #pragma unroll
    for(int n = 0; n < 4; n++) acc[m][n] = (f32x4){0.f, 0.f, 0.f, 0.f};
  int arow0 = wm * 32 + l15;

  int qoff[2][4];
  #pragma unroll
  for(int ks = 0; ks < 2; ks++)
    #pragma unroll
    for(int nf = 0; nf < 4; nf++){
      int oc = wn * 64 + nf * 16 + l15;
      int byte = (oc << 7) | (((ks << 6) | (lgp << 4)) ^ ((oc & 7) << 4));
      qoff[ks][nf] = byte >> 1;
    }

  for(int kw = 0; kw < 64; kw++){
    int cur = kw & 1;
    if(kw < 63){
      const u16_t* g = wsrc + (size_t)(kw + 1) * 8192 + tid * 8;
      #pragma unroll
      for(int j = 0; j < 4; j++)
        gld_lds16(g + j * 2048, &wtile[cur ^ 1][j * 2048 + wid * 512]);
      asm volatile("s_waitcnt vmcnt(4)" ::: "memory");   // kw's 4 loads retired
    } else {
      asm volatile("s_waitcnt vmcnt(0)" ::: "memory");
    }
    __builtin_amdgcn_s_barrier();
    const u16_t* wt = wtile[cur];
    #pragma unroll
    for(int ks = 0; ks < 2; ks++){
      bf16x8 a0 = *(const bf16x8*)(strip + (arow0 + kw) * 72 + ks * 32 + lgp * 8);
      bf16x8 a1 = *(const bf16x8*)(strip + (arow0 + 16 + kw) * 72 + ks * 32 + lgp * 8);
      bf16x8 q0 = *(const bf16x8*)(wt + qoff[ks][0]);
      bf16x8 q1 = *(const bf16x8*)(wt + qoff[ks][1]);
      bf16x8 q2 = *(const bf16x8*)(wt + qoff[ks][2]);
      bf16x8 q3 = *(const bf16x8*)(wt + qoff[ks][3]);
      acc[0][0] = MFMA16(a0, q0, acc[0][0]);
      acc[0][1] = MFMA16(a0, q1, acc[0][1]);
      acc[0][2] = MFMA16(a0, q2, acc[0][2]);
      acc[0][3] = MFMA16(a0, q3, acc[0][3]);
      acc[1][0] = MFMA16(a1, q0, acc[1][0]);
      acc[1][1] = MFMA16(a1, q1, acc[1][1]);
      acc[1][2] = MFMA16(a1, q2, acc[1][2]);
      acc[1][3] = MFMA16(a1, q3, acc[1][3]);
    }
    asm volatile("s_waitcnt lgkmcnt(0)" ::: "memory");   // buf reads complete
    __builtin_amdgcn_s_barrier();                        // before next overwrite
  }

  float* dst = part + ((size_t)kh * BT + (size_t)mt * 64) * 128;
  #pragma unroll
  for(int mf = 0; mf < 2; mf++)
    #pragma unroll
    for(int nf = 0; nf < 4; nf++)
      #pragma unroll
      for(int r = 0; r < 4; r++){
        int row = wm * 32 + mf * 16 + lgp * 4 + r;
        int col = wn * 64 + nf * 16 + l15;
        dst[row * 128 + col] = acc[mf][nf][r];
      }
}

// ---------------- fused GLU + attention block, MFMA (16 rows / WG) ----------------
__global__ __launch_bounds__(256) void k_attn(const float* __restrict__ part,
    const float* __restrict__ convb, const float* __restrict__ ycur,
    const u16_t* __restrict__ eabf, const u16_t* __restrict__ eoT,
    const float* __restrict__ Wce, const float* __restrict__ bce,
    const float* __restrict__ Wec, const float* __restrict__ bec,
    float* __restrict__ ynext, u16_t* __restrict__ ybf){
  int bid = blockIdx.x;            // 0..255
  int row0 = bid << 4;
  int b = row0 >> 9;
  int tid = threadIdx.x;
  int lane = tid & 63, w = tid >> 6;
  int l15 = lane & 15, lgp = lane >> 4;

  __shared__ float yml[16][68];
  __shared__ float pgS[16][68];
  __shared__ u16_t pgb[16][72];
  __shared__ float aof[4][64][17];
  __shared__ float aosm[16][68];
  __shared__ float reds[4][16];
  __shared__ float invt[16];

  // phase 0: GLU + residual
  for(int i = tid; i < 1024; i += 256){
    int r = i >> 6, h = i & 63;
    int grow = row0 + r;
    float ca = convb[h], cb = convb[64 + h];
    #pragma unroll
    for(int kh = 0; kh < 5; kh++){
      int bpp = b + kh - 2;
      if(bpp >= 0 && bpp < NB){
        const float* p = part + ((size_t)kh * BT + grow) * 128;
        ca += p[h]; cb += p[64 + h];
      }
    }
    float sig = 1.f / (1.f + __expf(-cb));
    yml[r][h] = (ca * sig + ycur[(size_t)grow * 64 + h]) * SQH;
  }
  __syncthreads();
  // phase 0b: pg logits = yml @ Wce + bce
  {
    int h = tid & 63, g = tid >> 6;
    float a0 = bce[h], a1 = a0, a2 = a0, a3 = a0;
    #pragma unroll 16
    for(int e = 0; e < 64; e++){
      float wv = Wce[e * 64 + h];
      a0 = fmaf(yml[g * 4 + 0][e], wv, a0);
      a1 = fmaf(yml[g * 4 + 1][e], wv, a1);
      a2 = fmaf(yml[g * 4 + 2][e], wv, a2);
      a3 = fmaf(yml[g * 4 + 3][e], wv, a3);
    }
    pgS[g * 4 + 0][h] = a0; pgS[g * 4 + 1][h] = a1;
    pgS[g * 4 + 2][h] = a2; pgS[g * 4 + 3][h] = a3;
  }
  __syncthreads();
  // phase 1: softmax over 64, normalized pg -> bf16
  {
    int r = tid >> 5, j = tid & 31;
    #pragma unroll
    for(int rr = r; rr < 16; rr += 8){
      float v1 = __expf(pgS[rr][j]), v2 = __expf(pgS[rr][j + 32]);
      float s = v1 + v2;
      s += __shfl_xor(s, 1); s += __shfl_xor(s, 2); s += __shfl_xor(s, 4);
      s += __shfl_xor(s, 8); s += __shfl_xor(s, 16);
      float inv = 1.f / s;
      pgb[rr][j] = f2bf(v1 * inv); pgb[rr][j + 32] = f2bf(v2 * inv);
    }
  }
  __syncthreads();

  // phase 2: per-wave 256-s slice: S^T = mfma(ea, pg); P=exp; AV = mfma(eoT, P^T)
  bf16x8 qpg0 = *(const bf16x8*)&pgb[l15][lgp * 8];
  bf16x8 qpg1 = *(const bf16x8*)&pgb[l15][32 + lgp * 8];
  float sumacc = 0.f;
  f32x4 ao[4];
  #pragma unroll
  for(int et = 0; et < 4; et++) ao[et] = (f32x4){0.f, 0.f, 0.f, 0.f};
  const u16_t* eab = eabf + ((size_t)b * NS + w * 256) * 64;
  const u16_t* eob = eoT + (size_t)b * 64 * NS + w * 256;
  for(int sc = 0; sc < 8; sc++){
    int sb = sc * 32;
    const u16_t* ar = eab + (size_t)(sb + l15) * 64 + lgp * 8;
    bf16x8 a00 = *(const bf16x8*)ar;
    bf16x8 a01 = *(const bf16x8*)(ar + 32);
    bf16x8 a10 = *(const bf16x8*)(ar + 1024);
    bf16x8 a11 = *(const bf16x8*)(ar + 1024 + 32);
    f32x4 s0 = {0.f, 0.f, 0.f, 0.f}, s1 = {0.f, 0.f, 0.f, 0.f};
    s0 = MFMA16(a00, qpg0, s0); s0 = MFMA16(a01, qpg1, s0);
    s1 = MFMA16(a10, qpg0, s1); s1 = MFMA16(a11, qpg1, s1);
    float p00 = __expf(s0[0]), p01 = __expf(s0[1]), p02 = __expf(s0[2]), p03 = __expf(s0[3]);
    float p10 = __expf(s1[0]), p11 = __expf(s1[1]), p12 = __expf(s1[2]), p13 = __expf(s1[3]);
    sumacc += (p00 + p01) + (p02 + p03) + (p10 + p11) + (p12 + p13);
    u32_t A0, B0, A1, B1;
    asm("v_cvt_pk_bf16_f32 %0, %1, %2" : "=v"(A0) : "v"(p00), "v"(p01));
    asm("v_cvt_pk_bf16_f32 %0, %1, %2" : "=v"(B0) : "v"(p02), "v"(p03));
    asm("v_cvt_pk_bf16_f32 %0, %1, %2" : "=v"(A1) : "v"(p10), "v"(p11));
    asm("v_cvt_pk_bf16_f32 %0, %1, %2" : "=v"(B1) : "v"(p12), "v"(p13));
    int src0 = l15 + ((lgp & 1) << 5);
    int src1 = src0 + 16;
    u32_t w0a = (u32_t)__shfl((int)A0, src0, 64), w0b = (u32_t)__shfl((int)A1, src0, 64);
    u32_t w1a = (u32_t)__shfl((int)B0, src0, 64), w1b = (u32_t)__shfl((int)B1, src0, 64);
    u32_t w2a = (u32_t)__shfl((int)A0, src1, 64), w2b = (u32_t)__shfl((int)A1, src1, 64);
    u32_t w3a = (u32_t)__shfl((int)B0, src1, 64), w3b = (u32_t)__shfl((int)B1, src1, 64);
    bool hi = lgp >= 2;
    union { u32_t u[4]; bf16x8 v; } bav;
    bav.u[0] = hi ? w0b : w0a; bav.u[1] = hi ? w1b : w1a;
    bav.u[2] = hi ? w2b : w2a; bav.u[3] = hi ? w3b : w3a;
    #pragma unroll
    for(int et = 0; et < 4; et++){
      const u16_t* er = eob + (size_t)(et * 16 + l15) * NS + sb + lgp * 8;
      bf16x8 ae = *(const bf16x8*)er;
      ao[et] = MFMA16(ae, bav.v, ao[et]);
    }
  }
  sumacc += __shfl_xor(sumacc, 16);
  sumacc += __shfl_xor(sumacc, 32);
  if(lane < 16) reds[w][l15] = sumacc;
  #pragma unroll
  for(int et = 0; et < 4; et++)
    #pragma unroll
    for(int r = 0; r < 4; r++)
      aof[w][et * 16 + lgp * 4 + r][l15] = ao[et][r];
  __syncthreads();
  if(tid < 16) invt[tid] = ATTN_SCALE / (reds[0][tid] + reds[1][tid] + reds[2][tid] + reds[3][tid]);
  __syncthreads();
  // phase 3: sum wave partials, scale, transpose to [t][e]
  for(int i = tid; i < 1024; i += 256){
    int e = i >> 4, t = i & 15;
    aosm[t][e] = (aof[0][e][t] + aof[1][e][t] + aof[2][e][t] + aof[3][e][t]) * invt[t];
  }
  __syncthreads();
  // phase 4: y logits = aosm @ Wec + bec
  {
    int h = tid & 63, g = tid >> 6;
    float a0 = bec[h], a1 = a0, a2 = a0, a3 = a0;
    #pragma unroll 16
    for(int e = 0; e < 64; e++){
      float wv = Wec[e * 64 + h];
      a0 = fmaf(aosm[g * 4 + 0][e], wv, a0);
      a1 = fmaf(aosm[g * 4 + 1][e], wv, a1);
      a2 = fmaf(aosm[g * 4 + 2][e], wv, a2);
      a3 = fmaf(aosm[g * 4 + 3][e], wv, a3);
    }
    pgS[g * 4 + 0][h] = a0; pgS[g * 4 + 1][h] = a1;
    pgS[g * 4 + 2][h] = a2; pgS[g * 4 + 3][h] = a3;
  }
  __syncthreads();
  // phase 5: softmax over 64 + store f32 y and bf16 padded image
  {
    int r = tid >> 5, j = tid & 31;
    #pragma unroll
    for(int rr = r; rr < 16; rr += 8){
      float v1 = __expf(pgS[rr][j]), v2 = __expf(pgS[rr][j + 32]);
      float s = v1 + v2;
      s += __shfl_xor(s, 1); s += __shfl_xor(s, 2); s += __shfl_xor(s, 4);
      s += __shfl_xor(s, 8); s += __shfl_xor(s, 16);
      float inv = 1.f / s;
      float o1 = v1 * inv, o2 = v2 * inv;
      int grow = row0 + rr;
      ynext[(size_t)grow * 64 + j] = o1;
      ynext[(size_t)grow * 64 + j + 32] = o2;
      size_t yb = ((size_t)(grow >> 9) * 576 + (grow & 511) + 31) * 64;
      ybf[yb + j] = f2bf(o1);
      ybf[yb + j + 32] = f2bf(o2);
    }
  }
}

// ---------------- y2 = relu(((y+dl1)*SQ)@W2+b2) -> bf16; zero esum ----------------
__global__ void k_w2(const float* __restrict__ y3, const float* __restrict__ dl1v,
                     const float* __restrict__ W2, const float* __restrict__ b2,
                     u16_t* __restrict__ y2bf, float* __restrict__ esum){
  int r0 = blockIdx.x * 4, tid = threadIdx.x;
  __shared__ float xs[4][64];
  xs[tid >> 6][tid & 63] = (y3[(size_t)r0 * 64 + tid] + dl1v[(size_t)r0 * 64 + tid]) * SQH;
  __syncthreads();
  int h = tid & 63, rr = tid >> 6;
  float acc = b2[h];
  #pragma unroll 16
  for(int e = 0; e < 64; e++) acc = fmaf(xs[rr][e], W2[e * 64 + h], acc);
  y2bf[(size_t)(r0 + rr) * 64 + h] = f2bf(fmaxf(acc, 0.f));
  if(tid < 4) esum[r0 + tid] = 0.f;
}

// ---------------- V-GEMM pass A ----------------
__global__ __launch_bounds__(256) void k_va(const u16_t* __restrict__ y2bf,
    const u16_t* __restrict__ W3t, const float* __restrict__ b3, float* __restrict__ esum){
  int m0 = blockIdx.x << 6, ns = blockIdx.y;
  int tid = threadIdx.x, lane = tid & 63, w = tid >> 6;
  int l15 = lane & 15, lgp = lane >> 4;
  bf16x8 a[4][2];
  #pragma unroll
  for(int mg = 0; mg < 4; mg++){
    const u16_t* ar = y2bf + ((size_t)(m0 + mg * 16 + l15) << 6) + lgp * 8;
    a[mg][0] = *(const bf16x8*)ar;
    a[mg][1] = *(const bf16x8*)(ar + 32);
  }
  float sums[4][4];
  #pragma unroll
  for(int mg = 0; mg < 4; mg++)
    #pragma unroll
    for(int r = 0; r < 4; r++) sums[mg][r] = 0.f;

  int nb0 = ns * 1600 + w * 400;
  for(int fi = 0; fi < 25; fi++){
    int n = nb0 + fi * 16 + l15;
    const u16_t* bp2 = W3t + ((size_t)n << 6) + lgp * 8;
    bf16x8 q0 = *(const bf16x8*)bp2;
    bf16x8 q1 = *(const bf16x8*)(bp2 + 32);
    float bias = b3[n];
    #pragma unroll
    for(int mg = 0; mg < 4; mg++){
      f32x4 acc = {0.f, 0.f, 0.f, 0.f};
      acc = MFMA16(a[mg][0], q0, acc);
      acc = MFMA16(a[mg][1], q1, acc);
      #pragma unroll
      for(int r = 0; r < 4; r++){
        float z = fmaxf(acc[r] + bias, 0.f);
        sums[mg][r] += __expf(z);
      }
    }
  }
  #pragma unroll
  for(int mg = 0; mg < 4; mg++)
    #pragma unroll
    for(int r = 0; r < 4; r++){
      float v = sums[mg][r];
      v += __shfl_xor(v, 1); v += __shfl_xor(v, 2);
      v += __shfl_xor(v, 4); v += __shfl_xor(v, 8);
      if(l15 == 0) atomicAdd(&esum[m0 + mg * 16 + lgp * 4 + r], v);
    }
}

// ---------------- V-GEMM pass B ----------------
__global__ __launch_bounds__(256) void k_vb(const u16_t* __restrict__ y2bf,
    const u16_t* __restrict__ W3t, const float* __restrict__ b3,
    const float* __restrict__ esum, float* __restrict__ out){
  int m0 = blockIdx.x << 6, ns = blockIdx.y;
  int tid = threadIdx.x, lane = tid & 63, w = tid >> 6;
  int l15 = lane & 15, lgp = lane >> 4;
  __shared__ float obuf[64][84];
  bf16x8 a[4][2];
  #pragma unroll
  for(int mg = 0; mg < 4; mg++){
    const u16_t* ar = y2bf + ((size_t)(m0 + mg * 16 + l15) << 6) + lgp * 8;
    a[mg][0] = *(const bf16x8*)ar;
    a[mg][1] = *(const bf16x8*)(ar + 32);
  }
  float invs[4][4];
  #pragma unroll
  for(int mg = 0; mg < 4; mg++)
    #pragma unroll
    for(int r = 0; r < 4; r++) invs[mg][r] = 1.f / esum[m0 + mg * 16 + lgp * 4 + r];

  int cb0 = ns * 1600;
  for(int si = 0; si < 25; si++){
    int cb = cb0 + si * 64;
    int n = cb + w * 16 + l15;
    const u16_t* bp2 = W3t + ((size_t)n << 6) + lgp * 8;
    bf16x8 q0 = *(const bf16x8*)bp2;
    bf16x8 q1 = *(const bf16x8*)(bp2 + 32);
    float bias = b3[n];
    #pragma unroll
    for(int mg = 0; mg < 4; mg++){
      f32x4 acc = {0.f, 0.f, 0.f, 0.f};
      acc = MFMA16(a[mg][0], q0, acc);
      acc = MFMA16(a[mg][1], q1, acc);
      #pragma unroll
      for(int r = 0; r < 4; r++){
        float z = fmaxf(acc[r] + bias, 0.f);
        obuf[mg * 16 + lgp * 4 + r][w * 16 + l15] = __expf(z) * invs[mg][r];
      }
    }
    __syncthreads();
    #pragma unroll
    for(int p = 0; p < 4; p++){
      int row = p * 16 + (tid >> 4);
      float4 v = *(const float4*)&obuf[row][(tid & 15) * 4];
      *(float4*)&out[(size_t)(m0 + row) * NV + cb + (tid & 15) * 4] = v;
    }
    __syncthreads();
  }
}

extern "C" void kernel_launch(void* const* d_in, const int* in_sizes, int n_in,
                              void* d_out, int out_size, void* d_ws, size_t ws_size,
                              hipStream_t stream){
  const float* input_x = (const float*)d_in[0];
  const float* enc_out = (const float*)d_in[1];
  const float* enc_att = (const float*)d_in[2];
  const float* W1    = (const float*)d_in[3];
  const float* b1    = (const float*)d_in[4];
  const float* convW = (const float*)d_in[5];
  const float* convb = (const float*)d_in[6];
  const float* Wce   = (const float*)d_in[7];
  const float* bce   = (const float*)d_in[8];
  const float* Wec   = (const float*)d_in[9];
  const float* bec   = (const float*)d_in[10];
  const float* W2    = (const float*)d_in[11];
  const float* b2    = (const float*)d_in[12];
  const float* W3    = (const float*)d_in[13];
  const float* b3    = (const float*)d_in[14];

  char* ws = (char*)d_ws;
  u16_t* Wt    = (u16_t*)(ws);                 // 5,242,880 B
  u16_t* W3t   = (u16_t*)(ws + 5242880);       // 4,096,000 B
  float* dl1v  = (float*)(ws + 9338880);       // 1,048,576 B
  float* yB    = (float*)(ws + 11436032);      // 1,048,576 B
  u16_t* ybf   = (u16_t*)(ws + 12484608);      //   589,824 B
  float* part  = (float*)(ws + 13074432);      // 10,485,760 B
  u16_t* y2bf  = (u16_t*)(ws + 23560192);      //   524,288 B
  float* esum  = (float*)(ws + 24084480);      //    16,384 B
  u16_t* eabf  = (u16_t*)(ws + 24100864);      // 1,048,576 B
  u16_t* eoT   = (u16_t*)(ws + 25149440);      // 1,048,576 B
  float* outp  = (float*)d_out;

  k_zpad<<<dim3(128), dim3(256), 0, stream>>>(ybf);
  k_prep_convw<<<dim3(320), dim3(256), 0, stream>>>(convW, Wt);
  k_prep_w3<<<dim3(125), dim3(256), 0, stream>>>(W3, W3t);
  k_prep_ea<<<dim3(128), dim3(256), 0, stream>>>(enc_att, enc_out, eabf, eoT);
  k_dl1<<<dim3(1024), dim3(256), 0, stream>>>(input_x, W1, b1, dl1v, ybf);

  const float* ycur = dl1v;
  for(int it = 0; it < 3; it++){
    k_conv<<<dim3(64, 5), dim3(256), 0, stream>>>(ybf, Wt, part);
    k_attn<<<dim3(256), dim3(256), 0, stream>>>(part, convb, ycur, eabf, eoT,
                                                Wce, bce, Wec, bec, yB, ybf);
    ycur = yB;
  }

  k_w2<<<dim3(1024), dim3(256), 0, stream>>>(yB, dl1v, W2, b2, y2bf, esum);
  k_va<<<dim3(64, 20), dim3(256), 0, stream>>>(y2bf, W3t, b3, esum);
  k_vb<<<dim3(64, 20), dim3(256), 0, stream>>>(y2bf, W3t, b3, esum, outp);
}